// Round 9
// baseline (430.362 us; speedup 1.0000x reference)
//
#include <hip/hip_runtime.h>

// FWHT of 2^26 fp32, two passes, bf16 column-blocked row-paired intermediate.
//   View: data[2048 rows][32768 cols] (row = bits 15..25, col = bits 0..14).
//   ws layout (bf16): ushort ws[1024 colblk][1024 rowpair][32 col][2 parity]
//     -> uint4 granularity: 8 ushorts = 4 cols x 2 rows, full 128B lines both ways.
//   Pass 1 (fwht_low15_paircb): block b owns rows 2b,2b+1. Bits 0..14 per row
//     (regs: 0,1,11..14; LDS 64KB: 2..10 via 3 b128 exchanges, XOR-swizzled).
//     Row A's bf16 result stashed in 32 VGPRs; after row B, interleaved uint4
//     writes -> 8x128B full lines per wave-instr. 2 blocks/CU.
//   Pass 2 (fwht_high11_cb): block = one colblk; input = 128KB contiguous.
//     u32 loads (2 bf16), phase A = 6-bit ladder over {parity(bit15), jp(21..25)},
//     LDS transpose (2x128KB chunks), phase B = 5-bit ladder (16..20), fp32
//     stores as consecutive-row 128B lines.
// Every global bit butterflied exactly once; stages commute == reference.
// Error: one bf16 RNE round of the mid values -> absmax ~256 (measured R8),
// threshold 947. Fallback to all-fp32 2-pass path if ws_size < 128 MB.

typedef float nvf4 __attribute__((ext_vector_type(4)));

__device__ __forceinline__ float4 add4(float4 a, float4 b) {
    return make_float4(a.x + b.x, a.y + b.y, a.z + b.z, a.w + b.w);
}
__device__ __forceinline__ float4 sub4(float4 a, float4 b) {
    return make_float4(a.x - b.x, a.y - b.y, a.z - b.z, a.w - b.w);
}
// LDS float4-index swizzle: conflict-free for strides {1,8,64,512} patterns used.
__device__ __forceinline__ int SWZ(int q) { return q ^ ((q >> 3) & 7); }

__device__ __forceinline__ unsigned int bfp(float x) {   // fp32 -> bf16 RNE
    unsigned int u = __builtin_bit_cast(unsigned int, x);
    return (u + 0x7fffu + ((u >> 16) & 1u)) >> 16;
}
__device__ __forceinline__ float bf2f(unsigned int h) {  // low16 bf16 -> fp32
    unsigned int u = h << 16;
    return __builtin_bit_cast(float, u);
}

__device__ __forceinline__ void lad3(float4* u) {        // 3-stage ladder, 8 quads
    #pragma unroll
    for (int h = 1; h < 8; h <<= 1) {
        #pragma unroll
        for (int i = 0; i < 8; i += 2 * h) {
            #pragma unroll
            for (int k = 0; k < h; ++k) {
                float4 a = u[i + k], b = u[i + k + h];
                u[i + k] = add4(a, b);
                u[i + k + h] = sub4(a, b);
            }
        }
    }
}

// ---------------- Pass 1: bits 0..14, rows 2b & 2b+1, paired bf16 output ----
__global__ __launch_bounds__(512, 4) void fwht_low15_paircb(
        const float* __restrict__ in, uint4* __restrict__ ws4) {
    __shared__ float4 lds4[4096];                    // 64 KB
    const int t = threadIdx.x;                       // 0..511
    const int rp = blockIdx.x;                       // row pair 0..1023
    unsigned int sa[32];                             // row-A packed bf16 stash

    #pragma unroll
    for (int rr = 0; rr < 2; ++rr) {
        const nvf4* in4 =
            reinterpret_cast<const nvf4*>(in + ((size_t)(2 * rp + rr) << 15));
        float4 v[16];
        #pragma unroll
        for (int k = 0; k < 16; ++k) {
            nvf4 xv = __builtin_nontemporal_load(in4 + t + 512 * k);
            float a0 = xv[0] + xv[1], a1 = xv[0] - xv[1];
            float a2 = xv[2] + xv[3], a3 = xv[2] - xv[3];
            v[k] = make_float4(a0 + a2, a1 + a3, a0 - a2, a1 - a3);
        }
        // k-ladder: quad bits 9..12 = float bits 11..14
        #pragma unroll
        for (int h = 1; h < 16; h <<= 1) {
            #pragma unroll
            for (int i = 0; i < 16; i += 2 * h) {
                #pragma unroll
                for (int k = 0; k < h; ++k) {
                    float4 a = v[i + k], b = v[i + k + h];
                    v[i + k] = add4(a, b);
                    v[i + k + h] = sub4(a, b);
                }
            }
        }

        #pragma unroll
        for (int hf = 0; hf < 2; ++hf) {
            float4* u = v + hf * 8;
            if (rr || hf) __syncthreads();           // prior exchange-C reads done
            #pragma unroll
            for (int k2 = 0; k2 < 8; ++k2)
                lds4[SWZ((k2 << 9) | t)] = u[k2];
            __syncthreads();

            // Exchange A: float bits 2..4
            #pragma unroll
            for (int j = 0; j < 8; ++j) u[j] = lds4[SWZ((t << 3) | j)];
            lad3(u);
            #pragma unroll
            for (int j = 0; j < 8; ++j) lds4[SWZ((t << 3) | j)] = u[j];
            __syncthreads();

            // Exchange B: float bits 5..7
            const int bB = ((t >> 3) << 6) | (t & 7);
            #pragma unroll
            for (int j = 0; j < 8; ++j) u[j] = lds4[SWZ(bB | (j << 3))];
            lad3(u);
            #pragma unroll
            for (int j = 0; j < 8; ++j) lds4[SWZ(bB | (j << 3))] = u[j];
            __syncthreads();

            // Exchange C: float bits 8..10
            const int bC = ((t >> 6) << 9) | (t & 63);
            #pragma unroll
            for (int j = 0; j < 8; ++j) u[j] = lds4[SWZ(bC | (j << 6))];
            lad3(u);

            if (rr == 0) {
                #pragma unroll
                for (int j = 0; j < 8; ++j) {
                    sa[(hf * 8 + j) * 2]     = bfp(u[j].x) | (bfp(u[j].y) << 16);
                    sa[(hf * 8 + j) * 2 + 1] = bfp(u[j].z) | (bfp(u[j].w) << 16);
                }
            } else {
                #pragma unroll
                for (int j = 0; j < 8; ++j) {
                    unsigned int bx = bfp(u[j].x) | (bfp(u[j].y) << 16);
                    unsigned int by = bfp(u[j].z) | (bfp(u[j].w) << 16);
                    unsigned int ax = sa[(hf * 8 + j) * 2];
                    unsigned int ay = sa[(hf * 8 + j) * 2 + 1];
                    uint4 o;                          // A(c0)B(c0)A(c1)B(c1)...
                    o.x = (ax & 0xffffu) | (bx << 16);
                    o.y = (ax >> 16) | (bx & 0xffff0000u);
                    o.z = (ay & 0xffffu) | (by << 16);
                    o.w = (ay >> 16) | (by & 0xffff0000u);
                    const int q = (hf << 12) | bC | (j << 6);   // global quad
                    ws4[(size_t)(q >> 3) * 8192 + rp * 8 + (q & 7)] = o;
                }
            }
        }
    }
}

// ---------------- Pass 2: bits 15..25, one colblk per block ----------------
__global__ __launch_bounds__(1024) void fwht_high11_cb(
        const unsigned int* __restrict__ ws32, float* __restrict__ out) {
    __shared__ float lds[32768];                     // 128 KB (transpose buffer)
    const int t = threadIdx.x;
    const int c = t & 31;
    const int g = t >> 5;                            // 0..31
    const int cb = blockIdx.x;                       // colblk 0..1023
    const unsigned int* wsb = ws32 + (size_t)cb * 32768;

    // Load: u32 = {parity0, parity1} bf16 of (rowpair = g+32*jp, col c).
    // 64 lanes hit 256 consecutive bytes per instr; block input contiguous.
    float v[64];
    #pragma unroll
    for (int jp = 0; jp < 32; ++jp) {
        unsigned int u = wsb[(g + 32 * jp) * 32 + c];
        v[jp * 2]     = bf2f(u & 0xffffu);
        v[jp * 2 + 1] = bf2f(u >> 16);
    }

    // Phase A: 6-bit ladder over v (index bit0 = parity = global bit 15,
    // bits 1..5 = jp = global bits 21..25; bit order irrelevant).
    #pragma unroll
    for (int h = 1; h < 64; h <<= 1) {
        #pragma unroll
        for (int i = 0; i < 64; i += 2 * h) {
            #pragma unroll
            for (int k = 0; k < h; ++k) {
                float a = v[i + k], b = v[i + k + h];
                v[i + k] = a + b;
                v[i + k + h] = a - b;
            }
        }
    }

    // Transpose chunks over jq = jp*2+p; phase B: 5-bit ladder over g-dim
    // (row bits 1..5 = global bits 16..20); store fp32 full lines.
    #pragma unroll
    for (int m = 0; m < 2; ++m) {
        if (m) __syncthreads();
        #pragma unroll
        for (int jj = 0; jj < 32; ++jj)
            lds[jj * 1024 + g * 32 + c] = v[32 * m + jj];   // bank = c, free
        __syncthreads();

        float w[32];
        #pragma unroll
        for (int s = 0; s < 32; ++s)
            w[s] = lds[g * 1024 + s * 32 + c];       // reader: jq_loc = g
        #pragma unroll
        for (int h = 1; h < 32; h <<= 1) {
            #pragma unroll
            for (int i = 0; i < 32; i += 2 * h) {
                #pragma unroll
                for (int k = 0; k < h; ++k) {
                    float a = w[i + k], b = w[i + k + h];
                    w[i + k] = a + b;
                    w[i + k + h] = a - b;
                }
            }
        }
        // rows: r = 2s + 32*(g&~1) + (g&1) + 1024*m  (g here = reader's jq_loc)
        const int rbase = 1024 * m + 32 * (g & ~1) + (g & 1);
        #pragma unroll
        for (int s = 0; s < 32; ++s)
            out[((size_t)(rbase + 2 * s) << 15) + (size_t)cb * 32 + c] = w[s];
    }
}

// ---------------- Fallback: proven all-fp32 2-pass path (R6) ----------------
__global__ __launch_bounds__(512) void fwht_low15_f32(const float* __restrict__ in,
                                                      float* __restrict__ out) {
    __shared__ float4 lds4[4096];
    const int t = threadIdx.x;
    const size_t base4 = (size_t)blockIdx.x * 8192;
    const nvf4* in4 = reinterpret_cast<const nvf4*>(in) + base4;
    float4* out4 = reinterpret_cast<float4*>(out) + base4;
    float4 v[16];
    #pragma unroll
    for (int k = 0; k < 16; ++k) {
        nvf4 xv = __builtin_nontemporal_load(in4 + t + 512 * k);
        float a0 = xv[0] + xv[1], a1 = xv[0] - xv[1];
        float a2 = xv[2] + xv[3], a3 = xv[2] - xv[3];
        v[k] = make_float4(a0 + a2, a1 + a3, a0 - a2, a1 - a3);
    }
    #pragma unroll
    for (int h = 1; h < 16; h <<= 1) {
        #pragma unroll
        for (int i = 0; i < 16; i += 2 * h) {
            #pragma unroll
            for (int k = 0; k < h; ++k) {
                float4 a = v[i + k], b = v[i + k + h];
                v[i + k] = add4(a, b);
                v[i + k + h] = sub4(a, b);
            }
        }
    }
    #pragma unroll
    for (int hf = 0; hf < 2; ++hf) {
        float4* u = v + hf * 8;
        if (hf) __syncthreads();
        #pragma unroll
        for (int k2 = 0; k2 < 8; ++k2) lds4[SWZ((k2 << 9) | t)] = u[k2];
        __syncthreads();
        #pragma unroll
        for (int j = 0; j < 8; ++j) u[j] = lds4[SWZ((t << 3) | j)];
        lad3(u);
        #pragma unroll
        for (int j = 0; j < 8; ++j) lds4[SWZ((t << 3) | j)] = u[j];
        __syncthreads();
        const int bB = ((t >> 3) << 6) | (t & 7);
        #pragma unroll
        for (int j = 0; j < 8; ++j) u[j] = lds4[SWZ(bB | (j << 3))];
        lad3(u);
        #pragma unroll
        for (int j = 0; j < 8; ++j) lds4[SWZ(bB | (j << 3))] = u[j];
        __syncthreads();
        const int bC = ((t >> 6) << 9) | (t & 63);
        #pragma unroll
        for (int j = 0; j < 8; ++j) u[j] = lds4[SWZ(bC | (j << 6))];
        lad3(u);
        #pragma unroll
        for (int j = 0; j < 8; ++j) out4[(hf << 12) | bC | (j << 6)] = u[j];
    }
}

__global__ __launch_bounds__(1024) void fwht_high11_f32(float* __restrict__ data) {
    __shared__ float lds[32768];
    const int t = threadIdx.x;
    const int c = t & 31;
    const int g = t >> 5;
    const size_t col = (size_t)blockIdx.x * 32 + c;
    float v[64];
    #pragma unroll
    for (int j = 0; j < 64; ++j)
        v[j] = data[((size_t)(g + 32 * j) << 15) + col];
    #pragma unroll
    for (int h = 1; h < 64; h <<= 1) {
        #pragma unroll
        for (int i = 0; i < 64; i += 2 * h) {
            #pragma unroll
            for (int k = 0; k < h; ++k) {
                float a = v[i + k], b = v[i + k + h];
                v[i + k] = a + b;
                v[i + k + h] = a - b;
            }
        }
    }
    #pragma unroll
    for (int m = 0; m < 2; ++m) {
        if (m) __syncthreads();
        #pragma unroll
        for (int jj = 0; jj < 32; ++jj)
            lds[jj * 1024 + g * 32 + c] = v[32 * m + jj];
        __syncthreads();
        float w[32];
        #pragma unroll
        for (int s = 0; s < 32; ++s) w[s] = lds[g * 1024 + s * 32 + c];
        #pragma unroll
        for (int h = 1; h < 32; h <<= 1) {
            #pragma unroll
            for (int i = 0; i < 32; i += 2 * h) {
                #pragma unroll
                for (int k = 0; k < h; ++k) {
                    float a = w[i + k], b = w[i + k + h];
                    w[i + k] = a + b;
                    w[i + k + h] = a - b;
                }
            }
        }
        const int rowbase = 32 * (32 * m + g);
        #pragma unroll
        for (int s = 0; s < 32; ++s)
            data[((size_t)(rowbase + s) << 15) + col] = w[s];
    }
}

extern "C" void kernel_launch(void* const* d_in, const int* in_sizes, int n_in,
                              void* d_out, int out_size, void* d_ws, size_t ws_size,
                              hipStream_t stream) {
    const float* x = (const float*)d_in[0];
    float* out = (float*)d_out;
    const size_t need = (size_t)1 << 27;             // 128 MB bf16 intermediate
    if (ws_size >= need && d_ws != nullptr) {
        fwht_low15_paircb<<<1024, 512, 0, stream>>>(x, (uint4*)d_ws);
        fwht_high11_cb<<<1024, 1024, 0, stream>>>((const unsigned int*)d_ws, out);
    } else {
        fwht_low15_f32<<<2048, 512, 0, stream>>>(x, out);
        fwht_high11_f32<<<1024, 1024, 0, stream>>>(out);
    }
}

// Round 10
// 310.073 us; speedup vs baseline: 1.3879x; 1.3879x over previous
//
#include <hip/hip_runtime.h>

// FWHT of 2^26 fp32, two passes, bf16 colblk-major parity-major intermediate.
//   View: data[2048 rows][32768 cols] (row = bits 15..25, col = bits 0..14).
//   ws (bf16): ushort ws[1024 cb][1024 rowpair][2 parity][32 col]  (128 MB,
//     fits L3; each cb's P2 input is 128 KB CONTIGUOUS).
//   Pass 1 (fwht_low15_pair): block = rowpair, 1024 threads; waves 0-7 row A,
//     8-15 row B (no cross-row register stash -> no spills). Per row: R6's
//     proven structure (regs bits 0,1,11..14; 64KB LDS region: bits 2..10 via
//     3 XOR-swizzled b128 exchanges). bf16 uint2 stores: row-A and row-B waves
//     write the two 64B halves of each 128B line concurrently (same block).
//   Pass 2 (fwht_high11_cb): block = one cb; ushort loads (contiguous 128 KB),
//     phase A = 6-bit ladder {parity(bit15), jp(21..25)}, LDS transpose
//     (2 chunks x 128KB), phase B = 5-bit ladder (16..20), fp32 NT stores
//     (full 128B lines; NT keeps ws L3-resident during P2).
// Every global bit butterflied exactly once; stages commute == reference.
// Error: one bf16 RNE round of mid values -> absmax 256 (measured R8/R9),
// threshold 947. Fallback to all-fp32 2-pass path if ws_size < 128 MB.

typedef float nvf4 __attribute__((ext_vector_type(4)));

__device__ __forceinline__ float4 add4(float4 a, float4 b) {
    return make_float4(a.x + b.x, a.y + b.y, a.z + b.z, a.w + b.w);
}
__device__ __forceinline__ float4 sub4(float4 a, float4 b) {
    return make_float4(a.x - b.x, a.y - b.y, a.z - b.z, a.w - b.w);
}
__device__ __forceinline__ int SWZ(int q) { return q ^ ((q >> 3) & 7); }

__device__ __forceinline__ unsigned int bfp(float x) {   // fp32 -> bf16 RNE
    unsigned int u = __builtin_bit_cast(unsigned int, x);
    return (u + 0x7fffu + ((u >> 16) & 1u)) >> 16;
}
__device__ __forceinline__ float bf2f(unsigned short h) {
    unsigned int u = ((unsigned int)h) << 16;
    return __builtin_bit_cast(float, u);
}

__device__ __forceinline__ void lad3(float4* u) {
    #pragma unroll
    for (int h = 1; h < 8; h <<= 1) {
        #pragma unroll
        for (int i = 0; i < 8; i += 2 * h) {
            #pragma unroll
            for (int k = 0; k < h; ++k) {
                float4 a = u[i + k], b = u[i + k + h];
                u[i + k] = add4(a, b);
                u[i + k + h] = sub4(a, b);
            }
        }
    }
}

// ---------------- Pass 1: bits 0..14, rowpair per block, 1024 threads -------
__global__ __launch_bounds__(1024) void fwht_low15_pair(
        const float* __restrict__ in, uint2* __restrict__ ws2) {
    __shared__ float4 lds4[8192];                    // 128 KB: two 64KB regions
    const int t = threadIdx.x;
    const int tr = t >> 9;                           // 0 = row A, 1 = row B
    const int tp = t & 511;                          // thread-in-row
    const int rp = blockIdx.x;                       // rowpair 0..1023
    const int rb = tr << 12;                         // LDS region base (float4)
    const nvf4* in4 =
        reinterpret_cast<const nvf4*>(in) + ((size_t)(2 * rp + tr) << 13);

    float4 v[16];
    #pragma unroll
    for (int k = 0; k < 16; ++k) {
        nvf4 xv = __builtin_nontemporal_load(in4 + tp + 512 * k);
        float a0 = xv[0] + xv[1], a1 = xv[0] - xv[1];
        float a2 = xv[2] + xv[3], a3 = xv[2] - xv[3];
        v[k] = make_float4(a0 + a2, a1 + a3, a0 - a2, a1 - a3);
    }
    // k-ladder: quad bits 9..12 = float bits 11..14
    #pragma unroll
    for (int h = 1; h < 16; h <<= 1) {
        #pragma unroll
        for (int i = 0; i < 16; i += 2 * h) {
            #pragma unroll
            for (int k = 0; k < h; ++k) {
                float4 a = v[i + k], b = v[i + k + h];
                v[i + k] = add4(a, b);
                v[i + k + h] = sub4(a, b);
            }
        }
    }

    #pragma unroll
    for (int hf = 0; hf < 2; ++hf) {
        float4* u = v + hf * 8;
        if (hf) __syncthreads();                     // hf0 ExC reads done
        #pragma unroll
        for (int k2 = 0; k2 < 8; ++k2)
            lds4[rb + SWZ((k2 << 9) | tp)] = u[k2];
        __syncthreads();

        // Exchange A: float bits 2..4
        #pragma unroll
        for (int j = 0; j < 8; ++j) u[j] = lds4[rb + SWZ((tp << 3) | j)];
        lad3(u);
        #pragma unroll
        for (int j = 0; j < 8; ++j) lds4[rb + SWZ((tp << 3) | j)] = u[j];
        __syncthreads();

        // Exchange B: float bits 5..7
        const int bB = ((tp >> 3) << 6) | (tp & 7);
        #pragma unroll
        for (int j = 0; j < 8; ++j) u[j] = lds4[rb + SWZ(bB | (j << 3))];
        lad3(u);
        #pragma unroll
        for (int j = 0; j < 8; ++j) lds4[rb + SWZ(bB | (j << 3))] = u[j];
        __syncthreads();

        // Exchange C: float bits 8..10, then bf16 pack + store
        const int bC = ((tp >> 6) << 9) | (tp & 63);
        #pragma unroll
        for (int j = 0; j < 8; ++j) u[j] = lds4[rb + SWZ(bC | (j << 6))];
        lad3(u);
        #pragma unroll
        for (int j = 0; j < 8; ++j) {
            uint2 pk;
            pk.x = bfp(u[j].x) | (bfp(u[j].y) << 16);
            pk.y = bfp(u[j].z) | (bfp(u[j].w) << 16);
            const int q = (hf << 12) | bC | (j << 6);   // quad within row
            // ws[cb=q>>3][rp][tr][cols 4*(q&7)..+3] ; uint2 units
            ws2[(size_t)(q >> 3) * 16384 + rp * 16 + tr * 8 + (q & 7)] = pk;
        }
    }
}

// ---------------- Pass 2: bits 15..25, one cb per block ---------------------
__global__ __launch_bounds__(1024) void fwht_high11_cb(
        const unsigned short* __restrict__ ws16, float* __restrict__ out) {
    __shared__ float lds[32768];                     // 128 KB transpose buffer
    const int t = threadIdx.x;
    const int c = t & 31;
    const int g = t >> 5;                            // 0..31
    const int cb = blockIdx.x;                       // colblk 0..1023
    const unsigned short* wsb = ws16 + (size_t)cb * 65536;   // 128 KB contiguous

    // v[2*jp+p] = bf16(rowpair g+32*jp, parity p, col c)
    float v[64];
    #pragma unroll
    for (int jp = 0; jp < 32; ++jp) {
        const int base = (g + 32 * jp) * 64 + c;
        v[2 * jp]     = bf2f(wsb[base]);
        v[2 * jp + 1] = bf2f(wsb[base + 32]);
    }

    // Phase A: 6-bit ladder (index bit0 = parity = global bit 15,
    // bits 1..5 = jp = global bits 21..25)
    #pragma unroll
    for (int h = 1; h < 64; h <<= 1) {
        #pragma unroll
        for (int i = 0; i < 64; i += 2 * h) {
            #pragma unroll
            for (int k = 0; k < h; ++k) {
                float a = v[i + k], b = v[i + k + h];
                v[i + k] = a + b;
                v[i + k + h] = a - b;
            }
        }
    }

    // Transpose chunks; phase B: 5-bit ladder over s (global bits 16..20)
    #pragma unroll
    for (int m = 0; m < 2; ++m) {
        if (m) __syncthreads();
        #pragma unroll
        for (int jj = 0; jj < 32; ++jj)
            lds[jj * 1024 + g * 32 + c] = v[32 * m + jj];   // bank = c, free
        __syncthreads();

        float w[32];
        #pragma unroll
        for (int s = 0; s < 32; ++s)
            w[s] = lds[g * 1024 + s * 32 + c];
        #pragma unroll
        for (int h = 1; h < 32; h <<= 1) {
            #pragma unroll
            for (int i = 0; i < 32; i += 2 * h) {
                #pragma unroll
                for (int k = 0; k < h; ++k) {
                    float a = w[i + k], b = w[i + k + h];
                    w[i + k] = a + b;
                    w[i + k + h] = a - b;
                }
            }
        }
        // local row r' = (g&1) + 2*s + 32*(g&~1) + 1024*m
        const int rbase = 1024 * m + 32 * (g & ~1) + (g & 1);
        #pragma unroll
        for (int s = 0; s < 32; ++s)
            __builtin_nontemporal_store(
                w[s], &out[((size_t)(rbase + 2 * s) << 15) + (size_t)cb * 32 + c]);
    }
}

// ---------------- Fallback: proven all-fp32 2-pass path (R6) ----------------
__global__ __launch_bounds__(512) void fwht_low15_f32(const float* __restrict__ in,
                                                      float* __restrict__ out) {
    __shared__ float4 lds4[4096];
    const int t = threadIdx.x;
    const size_t base4 = (size_t)blockIdx.x * 8192;
    const nvf4* in4 = reinterpret_cast<const nvf4*>(in) + base4;
    float4* out4 = reinterpret_cast<float4*>(out) + base4;
    float4 v[16];
    #pragma unroll
    for (int k = 0; k < 16; ++k) {
        nvf4 xv = __builtin_nontemporal_load(in4 + t + 512 * k);
        float a0 = xv[0] + xv[1], a1 = xv[0] - xv[1];
        float a2 = xv[2] + xv[3], a3 = xv[2] - xv[3];
        v[k] = make_float4(a0 + a2, a1 + a3, a0 - a2, a1 - a3);
    }
    #pragma unroll
    for (int h = 1; h < 16; h <<= 1) {
        #pragma unroll
        for (int i = 0; i < 16; i += 2 * h) {
            #pragma unroll
            for (int k = 0; k < h; ++k) {
                float4 a = v[i + k], b = v[i + k + h];
                v[i + k] = add4(a, b);
                v[i + k + h] = sub4(a, b);
            }
        }
    }
    #pragma unroll
    for (int hf = 0; hf < 2; ++hf) {
        float4* u = v + hf * 8;
        if (hf) __syncthreads();
        #pragma unroll
        for (int k2 = 0; k2 < 8; ++k2) lds4[SWZ((k2 << 9) | t)] = u[k2];
        __syncthreads();
        #pragma unroll
        for (int j = 0; j < 8; ++j) u[j] = lds4[SWZ((t << 3) | j)];
        lad3(u);
        #pragma unroll
        for (int j = 0; j < 8; ++j) lds4[SWZ((t << 3) | j)] = u[j];
        __syncthreads();
        const int bB = ((t >> 3) << 6) | (t & 7);
        #pragma unroll
        for (int j = 0; j < 8; ++j) u[j] = lds4[SWZ(bB | (j << 3))];
        lad3(u);
        #pragma unroll
        for (int j = 0; j < 8; ++j) lds4[SWZ(bB | (j << 3))] = u[j];
        __syncthreads();
        const int bC = ((t >> 6) << 9) | (t & 63);
        #pragma unroll
        for (int j = 0; j < 8; ++j) u[j] = lds4[SWZ(bC | (j << 6))];
        lad3(u);
        #pragma unroll
        for (int j = 0; j < 8; ++j) out4[(hf << 12) | bC | (j << 6)] = u[j];
    }
}

__global__ __launch_bounds__(1024) void fwht_high11_f32(float* __restrict__ data) {
    __shared__ float lds[32768];
    const int t = threadIdx.x;
    const int c = t & 31;
    const int g = t >> 5;
    const size_t col = (size_t)blockIdx.x * 32 + c;
    float v[64];
    #pragma unroll
    for (int j = 0; j < 64; ++j)
        v[j] = data[((size_t)(g + 32 * j) << 15) + col];
    #pragma unroll
    for (int h = 1; h < 64; h <<= 1) {
        #pragma unroll
        for (int i = 0; i < 64; i += 2 * h) {
            #pragma unroll
            for (int k = 0; k < h; ++k) {
                float a = v[i + k], b = v[i + k + h];
                v[i + k] = a + b;
                v[i + k + h] = a - b;
            }
        }
    }
    #pragma unroll
    for (int m = 0; m < 2; ++m) {
        if (m) __syncthreads();
        #pragma unroll
        for (int jj = 0; jj < 32; ++jj)
            lds[jj * 1024 + g * 32 + c] = v[32 * m + jj];
        __syncthreads();
        float w[32];
        #pragma unroll
        for (int s = 0; s < 32; ++s) w[s] = lds[g * 1024 + s * 32 + c];
        #pragma unroll
        for (int h = 1; h < 32; h <<= 1) {
            #pragma unroll
            for (int i = 0; i < 32; i += 2 * h) {
                #pragma unroll
                for (int k = 0; k < h; ++k) {
                    float a = w[i + k], b = w[i + k + h];
                    w[i + k] = a + b;
                    w[i + k + h] = a - b;
                }
            }
        }
        const int rowbase = 32 * (32 * m + g);
        #pragma unroll
        for (int s = 0; s < 32; ++s)
            data[((size_t)(rowbase + s) << 15) + col] = w[s];
    }
}

extern "C" void kernel_launch(void* const* d_in, const int* in_sizes, int n_in,
                              void* d_out, int out_size, void* d_ws, size_t ws_size,
                              hipStream_t stream) {
    const float* x = (const float*)d_in[0];
    float* out = (float*)d_out;
    const size_t need = (size_t)1 << 27;             // 128 MB bf16 intermediate
    if (ws_size >= need && d_ws != nullptr) {
        fwht_low15_pair<<<1024, 1024, 0, stream>>>(x, (uint2*)d_ws);
        fwht_high11_cb<<<1024, 1024, 0, stream>>>((const unsigned short*)d_ws, out);
    } else {
        fwht_low15_f32<<<2048, 512, 0, stream>>>(x, out);
        fwht_high11_f32<<<1024, 1024, 0, stream>>>(out);
    }
}

// Round 11
// 183.126 us; speedup vs baseline: 2.3501x; 1.6932x over previous
//
#include <hip/hip_runtime.h>

// FWHT of 2^26 fp32, two passes, bf16 colblk-major parity-major intermediate.
//   View: data[2048 rows][32768 cols] (row = bits 15..25, col = bits 0..14).
//   ws (bf16): ushort ws[1024 cb][1024 rowpair][2 parity][32 col]  (128 MB;
//     each cb's P2 input is 128 KB CONTIGUOUS).
//   Pass 1 (fwht_low15_bf): R6's proven 512-thread 1-row/block kernel
//     (regs bits 0,1,11..14; 64 KB LDS: bits 2..10 via 3 XOR-swizzled b128
//     exchanges; NO launch-bounds occupancy arg -> no VGPR clamp/spill).
//     Epilogue packs bf16 uint2 -> ws: 8 x 64 B segments per wave-instr
//     (sector-granule; sibling-row block fills the other 64 B of each line).
//   Pass 2 (fwht_high11_cb): byte-identical to R10 (proven, ~75 us): block =
//     one cb; contiguous ushort loads, phase A = 6-bit ladder {bit15, 21..25},
//     LDS transpose (2 chunks), phase B = 5-bit ladder (16..20), fp32 NT
//     stores (full 128 B lines).
// Every global bit butterflied exactly once; stages commute == reference.
// Error: one bf16 RNE round of mid values -> absmax 256 (measured R8-R10),
// threshold 947. Fallback to all-fp32 2-pass path (R6) if ws too small.

typedef float nvf4 __attribute__((ext_vector_type(4)));

__device__ __forceinline__ float4 add4(float4 a, float4 b) {
    return make_float4(a.x + b.x, a.y + b.y, a.z + b.z, a.w + b.w);
}
__device__ __forceinline__ float4 sub4(float4 a, float4 b) {
    return make_float4(a.x - b.x, a.y - b.y, a.z - b.z, a.w - b.w);
}
__device__ __forceinline__ int SWZ(int q) { return q ^ ((q >> 3) & 7); }

__device__ __forceinline__ unsigned int bfp(float x) {   // fp32 -> bf16 RNE
    unsigned int u = __builtin_bit_cast(unsigned int, x);
    return (u + 0x7fffu + ((u >> 16) & 1u)) >> 16;
}
__device__ __forceinline__ float bf2f(unsigned short h) {
    unsigned int u = ((unsigned int)h) << 16;
    return __builtin_bit_cast(float, u);
}

__device__ __forceinline__ void lad3(float4* u) {
    #pragma unroll
    for (int h = 1; h < 8; h <<= 1) {
        #pragma unroll
        for (int i = 0; i < 8; i += 2 * h) {
            #pragma unroll
            for (int k = 0; k < h; ++k) {
                float4 a = u[i + k], b = u[i + k + h];
                u[i + k] = add4(a, b);
                u[i + k + h] = sub4(a, b);
            }
        }
    }
}

// ---------------- Pass 1: bits 0..14, one row per 512-thread block ----------
__global__ __launch_bounds__(512) void fwht_low15_bf(const float* __restrict__ in,
                                                     uint2* __restrict__ ws2) {
    __shared__ float4 lds4[4096];                    // 64 KB
    const int t = threadIdx.x;                       // 0..511
    const int row = blockIdx.x;                      // 0..2047
    const int rp = row >> 1;
    const int par = row & 1;
    const nvf4* in4 = reinterpret_cast<const nvf4*>(in) + ((size_t)row << 13);

    float4 v[16];
    #pragma unroll
    for (int k = 0; k < 16; ++k) {
        nvf4 xv = __builtin_nontemporal_load(in4 + t + 512 * k);
        float a0 = xv[0] + xv[1], a1 = xv[0] - xv[1];
        float a2 = xv[2] + xv[3], a3 = xv[2] - xv[3];
        v[k] = make_float4(a0 + a2, a1 + a3, a0 - a2, a1 - a3);
    }
    // k-ladder: quad bits 9..12 = float bits 11..14
    #pragma unroll
    for (int h = 1; h < 16; h <<= 1) {
        #pragma unroll
        for (int i = 0; i < 16; i += 2 * h) {
            #pragma unroll
            for (int k = 0; k < h; ++k) {
                float4 a = v[i + k], b = v[i + k + h];
                v[i + k] = add4(a, b);
                v[i + k + h] = sub4(a, b);
            }
        }
    }

    #pragma unroll
    for (int hf = 0; hf < 2; ++hf) {
        float4* u = v + hf * 8;
        if (hf) __syncthreads();                     // hf0 ExC reads done
        #pragma unroll
        for (int k2 = 0; k2 < 8; ++k2)
            lds4[SWZ((k2 << 9) | t)] = u[k2];
        __syncthreads();

        // Exchange A: float bits 2..4
        #pragma unroll
        for (int j = 0; j < 8; ++j) u[j] = lds4[SWZ((t << 3) | j)];
        lad3(u);
        #pragma unroll
        for (int j = 0; j < 8; ++j) lds4[SWZ((t << 3) | j)] = u[j];
        __syncthreads();

        // Exchange B: float bits 5..7
        const int bB = ((t >> 3) << 6) | (t & 7);
        #pragma unroll
        for (int j = 0; j < 8; ++j) u[j] = lds4[SWZ(bB | (j << 3))];
        lad3(u);
        #pragma unroll
        for (int j = 0; j < 8; ++j) lds4[SWZ(bB | (j << 3))] = u[j];
        __syncthreads();

        // Exchange C: float bits 8..10, then bf16 pack + colblk store
        const int bC = ((t >> 6) << 9) | (t & 63);
        #pragma unroll
        for (int j = 0; j < 8; ++j) u[j] = lds4[SWZ(bC | (j << 6))];
        lad3(u);
        #pragma unroll
        for (int j = 0; j < 8; ++j) {
            uint2 pk;
            pk.x = bfp(u[j].x) | (bfp(u[j].y) << 16);
            pk.y = bfp(u[j].z) | (bfp(u[j].w) << 16);
            const int q = (hf << 12) | bC | (j << 6);   // quad within row
            // ws[cb=q>>3][rp][par][cols 4*(q&7)..+3]; uint2 units
            ws2[(size_t)(q >> 3) * 16384 + rp * 16 + par * 8 + (q & 7)] = pk;
        }
    }
}

// ---------------- Pass 2: bits 15..25, one cb per block (R10, proven) -------
__global__ __launch_bounds__(1024) void fwht_high11_cb(
        const unsigned short* __restrict__ ws16, float* __restrict__ out) {
    __shared__ float lds[32768];                     // 128 KB transpose buffer
    const int t = threadIdx.x;
    const int c = t & 31;
    const int g = t >> 5;                            // 0..31
    const int cb = blockIdx.x;                       // colblk 0..1023
    const unsigned short* wsb = ws16 + (size_t)cb * 65536;   // 128 KB contiguous

    float v[64];
    #pragma unroll
    for (int jp = 0; jp < 32; ++jp) {
        const int base = (g + 32 * jp) * 64 + c;
        v[2 * jp]     = bf2f(wsb[base]);
        v[2 * jp + 1] = bf2f(wsb[base + 32]);
    }

    // Phase A: 6-bit ladder (bit0 = parity = global bit 15, bits 1..5 = 21..25)
    #pragma unroll
    for (int h = 1; h < 64; h <<= 1) {
        #pragma unroll
        for (int i = 0; i < 64; i += 2 * h) {
            #pragma unroll
            for (int k = 0; k < h; ++k) {
                float a = v[i + k], b = v[i + k + h];
                v[i + k] = a + b;
                v[i + k + h] = a - b;
            }
        }
    }

    // Transpose chunks; phase B: 5-bit ladder over s (global bits 16..20)
    #pragma unroll
    for (int m = 0; m < 2; ++m) {
        if (m) __syncthreads();
        #pragma unroll
        for (int jj = 0; jj < 32; ++jj)
            lds[jj * 1024 + g * 32 + c] = v[32 * m + jj];   // bank = c, free
        __syncthreads();

        float w[32];
        #pragma unroll
        for (int s = 0; s < 32; ++s)
            w[s] = lds[g * 1024 + s * 32 + c];
        #pragma unroll
        for (int h = 1; h < 32; h <<= 1) {
            #pragma unroll
            for (int i = 0; i < 32; i += 2 * h) {
                #pragma unroll
                for (int k = 0; k < h; ++k) {
                    float a = w[i + k], b = w[i + k + h];
                    w[i + k] = a + b;
                    w[i + k + h] = a - b;
                }
            }
        }
        const int rbase = 1024 * m + 32 * (g & ~1) + (g & 1);
        #pragma unroll
        for (int s = 0; s < 32; ++s)
            __builtin_nontemporal_store(
                w[s], &out[((size_t)(rbase + 2 * s) << 15) + (size_t)cb * 32 + c]);
    }
}

// ---------------- Fallback: proven all-fp32 2-pass path (R6) ----------------
__global__ __launch_bounds__(512) void fwht_low15_f32(const float* __restrict__ in,
                                                      float* __restrict__ out) {
    __shared__ float4 lds4[4096];
    const int t = threadIdx.x;
    const size_t base4 = (size_t)blockIdx.x * 8192;
    const nvf4* in4 = reinterpret_cast<const nvf4*>(in) + base4;
    float4* out4 = reinterpret_cast<float4*>(out) + base4;
    float4 v[16];
    #pragma unroll
    for (int k = 0; k < 16; ++k) {
        nvf4 xv = __builtin_nontemporal_load(in4 + t + 512 * k);
        float a0 = xv[0] + xv[1], a1 = xv[0] - xv[1];
        float a2 = xv[2] + xv[3], a3 = xv[2] - xv[3];
        v[k] = make_float4(a0 + a2, a1 + a3, a0 - a2, a1 - a3);
    }
    #pragma unroll
    for (int h = 1; h < 16; h <<= 1) {
        #pragma unroll
        for (int i = 0; i < 16; i += 2 * h) {
            #pragma unroll
            for (int k = 0; k < h; ++k) {
                float4 a = v[i + k], b = v[i + k + h];
                v[i + k] = add4(a, b);
                v[i + k + h] = sub4(a, b);
            }
        }
    }
    #pragma unroll
    for (int hf = 0; hf < 2; ++hf) {
        float4* u = v + hf * 8;
        if (hf) __syncthreads();
        #pragma unroll
        for (int k2 = 0; k2 < 8; ++k2) lds4[SWZ((k2 << 9) | t)] = u[k2];
        __syncthreads();
        #pragma unroll
        for (int j = 0; j < 8; ++j) u[j] = lds4[SWZ((t << 3) | j)];
        lad3(u);
        #pragma unroll
        for (int j = 0; j < 8; ++j) lds4[SWZ((t << 3) | j)] = u[j];
        __syncthreads();
        const int bB = ((t >> 3) << 6) | (t & 7);
        #pragma unroll
        for (int j = 0; j < 8; ++j) u[j] = lds4[SWZ(bB | (j << 3))];
        lad3(u);
        #pragma unroll
        for (int j = 0; j < 8; ++j) lds4[SWZ(bB | (j << 3))] = u[j];
        __syncthreads();
        const int bC = ((t >> 6) << 9) | (t & 63);
        #pragma unroll
        for (int j = 0; j < 8; ++j) u[j] = lds4[SWZ(bC | (j << 6))];
        lad3(u);
        #pragma unroll
        for (int j = 0; j < 8; ++j) out4[(hf << 12) | bC | (j << 6)] = u[j];
    }
}

__global__ __launch_bounds__(1024) void fwht_high11_f32(float* __restrict__ data) {
    __shared__ float lds[32768];
    const int t = threadIdx.x;
    const int c = t & 31;
    const int g = t >> 5;
    const size_t col = (size_t)blockIdx.x * 32 + c;
    float v[64];
    #pragma unroll
    for (int j = 0; j < 64; ++j)
        v[j] = data[((size_t)(g + 32 * j) << 15) + col];
    #pragma unroll
    for (int h = 1; h < 64; h <<= 1) {
        #pragma unroll
        for (int i = 0; i < 64; i += 2 * h) {
            #pragma unroll
            for (int k = 0; k < h; ++k) {
                float a = v[i + k], b = v[i + k + h];
                v[i + k] = a + b;
                v[i + k + h] = a - b;
            }
        }
    }
    #pragma unroll
    for (int m = 0; m < 2; ++m) {
        if (m) __syncthreads();
        #pragma unroll
        for (int jj = 0; jj < 32; ++jj)
            lds[jj * 1024 + g * 32 + c] = v[32 * m + jj];
        __syncthreads();
        float w[32];
        #pragma unroll
        for (int s = 0; s < 32; ++s) w[s] = lds[g * 1024 + s * 32 + c];
        #pragma unroll
        for (int h = 1; h < 32; h <<= 1) {
            #pragma unroll
            for (int i = 0; i < 32; i += 2 * h) {
                #pragma unroll
                for (int k = 0; k < h; ++k) {
                    float a = w[i + k], b = w[i + k + h];
                    w[i + k] = a + b;
                    w[i + k + h] = a - b;
                }
            }
        }
        const int rowbase = 32 * (32 * m + g);
        #pragma unroll
        for (int s = 0; s < 32; ++s)
            data[((size_t)(rowbase + s) << 15) + col] = w[s];
    }
}

extern "C" void kernel_launch(void* const* d_in, const int* in_sizes, int n_in,
                              void* d_out, int out_size, void* d_ws, size_t ws_size,
                              hipStream_t stream) {
    const float* x = (const float*)d_in[0];
    float* out = (float*)d_out;
    const size_t need = (size_t)1 << 27;             // 128 MB bf16 intermediate
    if (ws_size >= need && d_ws != nullptr) {
        fwht_low15_bf<<<2048, 512, 0, stream>>>(x, (uint2*)d_ws);
        fwht_high11_cb<<<1024, 1024, 0, stream>>>((const unsigned short*)d_ws, out);
    } else {
        fwht_low15_f32<<<2048, 512, 0, stream>>>(x, out);
        fwht_high11_f32<<<1024, 1024, 0, stream>>>(out);
    }
}

// Round 12
// 176.565 us; speedup vs baseline: 2.4374x; 1.0372x over previous
//
#include <hip/hip_runtime.h>

// FWHT of 2^26 fp32, two passes, bf16 colblk-major parity-major intermediate.
//   View: data[2048 rows][32768 cols] (row = bits 15..25, col = bits 0..14).
//   ws (bf16): ushort ws[1024 cb][1024 rowpair][2 parity][32 col]  (128 MB;
//     each cb's P2 input is 128 KB CONTIGUOUS).
//   Pass 1 (fwht_low15_bf): R6-proven 512-thread 1-row/block kernel.
//     NEW vs R11: XCD-pairing block swizzle row=(bid&7)*256+(bid>>3) so both
//     64 B halves of every ws 128 B line are written by the SAME XCD
//     (kills cross-XCD false sharing / enables L2 write-combining).
//   Pass 2 (fwht_high11_cb): byte-identical to R10/R11 (proven).
// Every global bit butterflied exactly once; stages commute == reference.
// Error: one bf16 RNE round of mid values -> absmax 256 (measured R8-R11),
// threshold 947. Fallback to all-fp32 2-pass path (R6) if ws too small.

typedef float nvf4 __attribute__((ext_vector_type(4)));

__device__ __forceinline__ float4 add4(float4 a, float4 b) {
    return make_float4(a.x + b.x, a.y + b.y, a.z + b.z, a.w + b.w);
}
__device__ __forceinline__ float4 sub4(float4 a, float4 b) {
    return make_float4(a.x - b.x, a.y - b.y, a.z - b.z, a.w - b.w);
}
__device__ __forceinline__ int SWZ(int q) { return q ^ ((q >> 3) & 7); }

__device__ __forceinline__ unsigned int bfp(float x) {   // fp32 -> bf16 RNE
    unsigned int u = __builtin_bit_cast(unsigned int, x);
    return (u + 0x7fffu + ((u >> 16) & 1u)) >> 16;
}
__device__ __forceinline__ float bf2f(unsigned short h) {
    unsigned int u = ((unsigned int)h) << 16;
    return __builtin_bit_cast(float, u);
}

__device__ __forceinline__ void lad3(float4* u) {
    #pragma unroll
    for (int h = 1; h < 8; h <<= 1) {
        #pragma unroll
        for (int i = 0; i < 8; i += 2 * h) {
            #pragma unroll
            for (int k = 0; k < h; ++k) {
                float4 a = u[i + k], b = u[i + k + h];
                u[i + k] = add4(a, b);
                u[i + k + h] = sub4(a, b);
            }
        }
    }
}

// ---------------- Pass 1: bits 0..14, one row per 512-thread block ----------
__global__ __launch_bounds__(512) void fwht_low15_bf(const float* __restrict__ in,
                                                     uint2* __restrict__ ws2) {
    __shared__ float4 lds4[4096];                    // 64 KB
    const int t = threadIdx.x;                       // 0..511
    // XCD-pairing swizzle: 8 XCDs round-robin on blockIdx; give each XCD a
    // contiguous 256-row chunk so rowpair halves share an XCD. Bijective
    // (2048 = 8*256).
    const int row = ((blockIdx.x & 7) << 8) | (blockIdx.x >> 3);   // 0..2047
    const int rp = row >> 1;
    const int par = row & 1;
    const nvf4* in4 = reinterpret_cast<const nvf4*>(in) + ((size_t)row << 13);

    float4 v[16];
    #pragma unroll
    for (int k = 0; k < 16; ++k) {
        nvf4 xv = __builtin_nontemporal_load(in4 + t + 512 * k);
        float a0 = xv[0] + xv[1], a1 = xv[0] - xv[1];
        float a2 = xv[2] + xv[3], a3 = xv[2] - xv[3];
        v[k] = make_float4(a0 + a2, a1 + a3, a0 - a2, a1 - a3);
    }
    // k-ladder: quad bits 9..12 = float bits 11..14
    #pragma unroll
    for (int h = 1; h < 16; h <<= 1) {
        #pragma unroll
        for (int i = 0; i < 16; i += 2 * h) {
            #pragma unroll
            for (int k = 0; k < h; ++k) {
                float4 a = v[i + k], b = v[i + k + h];
                v[i + k] = add4(a, b);
                v[i + k + h] = sub4(a, b);
            }
        }
    }

    #pragma unroll
    for (int hf = 0; hf < 2; ++hf) {
        float4* u = v + hf * 8;
        if (hf) __syncthreads();                     // hf0 ExC reads done
        #pragma unroll
        for (int k2 = 0; k2 < 8; ++k2)
            lds4[SWZ((k2 << 9) | t)] = u[k2];
        __syncthreads();

        // Exchange A: float bits 2..4
        #pragma unroll
        for (int j = 0; j < 8; ++j) u[j] = lds4[SWZ((t << 3) | j)];
        lad3(u);
        #pragma unroll
        for (int j = 0; j < 8; ++j) lds4[SWZ((t << 3) | j)] = u[j];
        __syncthreads();

        // Exchange B: float bits 5..7
        const int bB = ((t >> 3) << 6) | (t & 7);
        #pragma unroll
        for (int j = 0; j < 8; ++j) u[j] = lds4[SWZ(bB | (j << 3))];
        lad3(u);
        #pragma unroll
        for (int j = 0; j < 8; ++j) lds4[SWZ(bB | (j << 3))] = u[j];
        __syncthreads();

        // Exchange C: float bits 8..10, then bf16 pack + colblk store
        const int bC = ((t >> 6) << 9) | (t & 63);
        #pragma unroll
        for (int j = 0; j < 8; ++j) u[j] = lds4[SWZ(bC | (j << 6))];
        lad3(u);
        #pragma unroll
        for (int j = 0; j < 8; ++j) {
            uint2 pk;
            pk.x = bfp(u[j].x) | (bfp(u[j].y) << 16);
            pk.y = bfp(u[j].z) | (bfp(u[j].w) << 16);
            const int q = (hf << 12) | bC | (j << 6);   // quad within row
            // ws[cb=q>>3][rp][par][cols 4*(q&7)..+3]; uint2 units
            ws2[(size_t)(q >> 3) * 16384 + rp * 16 + par * 8 + (q & 7)] = pk;
        }
    }
}

// ---------------- Pass 2: bits 15..25, one cb per block (proven) ------------
__global__ __launch_bounds__(1024) void fwht_high11_cb(
        const unsigned short* __restrict__ ws16, float* __restrict__ out) {
    __shared__ float lds[32768];                     // 128 KB transpose buffer
    const int t = threadIdx.x;
    const int c = t & 31;
    const int g = t >> 5;                            // 0..31
    const int cb = blockIdx.x;                       // colblk 0..1023
    const unsigned short* wsb = ws16 + (size_t)cb * 65536;   // 128 KB contiguous

    float v[64];
    #pragma unroll
    for (int jp = 0; jp < 32; ++jp) {
        const int base = (g + 32 * jp) * 64 + c;
        v[2 * jp]     = bf2f(wsb[base]);
        v[2 * jp + 1] = bf2f(wsb[base + 32]);
    }

    // Phase A: 6-bit ladder (bit0 = parity = global bit 15, bits 1..5 = 21..25)
    #pragma unroll
    for (int h = 1; h < 64; h <<= 1) {
        #pragma unroll
        for (int i = 0; i < 64; i += 2 * h) {
            #pragma unroll
            for (int k = 0; k < h; ++k) {
                float a = v[i + k], b = v[i + k + h];
                v[i + k] = a + b;
                v[i + k + h] = a - b;
            }
        }
    }

    // Transpose chunks; phase B: 5-bit ladder over s (global bits 16..20)
    #pragma unroll
    for (int m = 0; m < 2; ++m) {
        if (m) __syncthreads();
        #pragma unroll
        for (int jj = 0; jj < 32; ++jj)
            lds[jj * 1024 + g * 32 + c] = v[32 * m + jj];   // bank = c, free
        __syncthreads();

        float w[32];
        #pragma unroll
        for (int s = 0; s < 32; ++s)
            w[s] = lds[g * 1024 + s * 32 + c];
        #pragma unroll
        for (int h = 1; h < 32; h <<= 1) {
            #pragma unroll
            for (int i = 0; i < 32; i += 2 * h) {
                #pragma unroll
                for (int k = 0; k < h; ++k) {
                    float a = w[i + k], b = w[i + k + h];
                    w[i + k] = a + b;
                    w[i + k + h] = a - b;
                }
            }
        }
        const int rbase = 1024 * m + 32 * (g & ~1) + (g & 1);
        #pragma unroll
        for (int s = 0; s < 32; ++s)
            __builtin_nontemporal_store(
                w[s], &out[((size_t)(rbase + 2 * s) << 15) + (size_t)cb * 32 + c]);
    }
}

// ---------------- Fallback: proven all-fp32 2-pass path (R6) ----------------
__global__ __launch_bounds__(512) void fwht_low15_f32(const float* __restrict__ in,
                                                      float* __restrict__ out) {
    __shared__ float4 lds4[4096];
    const int t = threadIdx.x;
    const size_t base4 = (size_t)blockIdx.x * 8192;
    const nvf4* in4 = reinterpret_cast<const nvf4*>(in) + base4;
    float4* out4 = reinterpret_cast<float4*>(out) + base4;
    float4 v[16];
    #pragma unroll
    for (int k = 0; k < 16; ++k) {
        nvf4 xv = __builtin_nontemporal_load(in4 + t + 512 * k);
        float a0 = xv[0] + xv[1], a1 = xv[0] - xv[1];
        float a2 = xv[2] + xv[3], a3 = xv[2] - xv[3];
        v[k] = make_float4(a0 + a2, a1 + a3, a0 - a2, a1 - a3);
    }
    #pragma unroll
    for (int h = 1; h < 16; h <<= 1) {
        #pragma unroll
        for (int i = 0; i < 16; i += 2 * h) {
            #pragma unroll
            for (int k = 0; k < h; ++k) {
                float4 a = v[i + k], b = v[i + k + h];
                v[i + k] = add4(a, b);
                v[i + k + h] = sub4(a, b);
            }
        }
    }
    #pragma unroll
    for (int hf = 0; hf < 2; ++hf) {
        float4* u = v + hf * 8;
        if (hf) __syncthreads();
        #pragma unroll
        for (int k2 = 0; k2 < 8; ++k2) lds4[SWZ((k2 << 9) | t)] = u[k2];
        __syncthreads();
        #pragma unroll
        for (int j = 0; j < 8; ++j) u[j] = lds4[SWZ((t << 3) | j)];
        lad3(u);
        #pragma unroll
        for (int j = 0; j < 8; ++j) lds4[SWZ((t << 3) | j)] = u[j];
        __syncthreads();
        const int bB = ((t >> 3) << 6) | (t & 7);
        #pragma unroll
        for (int j = 0; j < 8; ++j) u[j] = lds4[SWZ(bB | (j << 3))];
        lad3(u);
        #pragma unroll
        for (int j = 0; j < 8; ++j) lds4[SWZ(bB | (j << 3))] = u[j];
        __syncthreads();
        const int bC = ((t >> 6) << 9) | (t & 63);
        #pragma unroll
        for (int j = 0; j < 8; ++j) u[j] = lds4[SWZ(bC | (j << 6))];
        lad3(u);
        #pragma unroll
        for (int j = 0; j < 8; ++j) out4[(hf << 12) | bC | (j << 6)] = u[j];
    }
}

__global__ __launch_bounds__(1024) void fwht_high11_f32(float* __restrict__ data) {
    __shared__ float lds[32768];
    const int t = threadIdx.x;
    const int c = t & 31;
    const int g = t >> 5;
    const size_t col = (size_t)blockIdx.x * 32 + c;
    float v[64];
    #pragma unroll
    for (int j = 0; j < 64; ++j)
        v[j] = data[((size_t)(g + 32 * j) << 15) + col];
    #pragma unroll
    for (int h = 1; h < 64; h <<= 1) {
        #pragma unroll
        for (int i = 0; i < 64; i += 2 * h) {
            #pragma unroll
            for (int k = 0; k < h; ++k) {
                float a = v[i + k], b = v[i + k + h];
                v[i + k] = a + b;
                v[i + k + h] = a - b;
            }
        }
    }
    #pragma unroll
    for (int m = 0; m < 2; ++m) {
        if (m) __syncthreads();
        #pragma unroll
        for (int jj = 0; jj < 32; ++jj)
            lds[jj * 1024 + g * 32 + c] = v[32 * m + jj];
        __syncthreads();
        float w[32];
        #pragma unroll
        for (int s = 0; s < 32; ++s) w[s] = lds[g * 1024 + s * 32 + c];
        #pragma unroll
        for (int h = 1; h < 32; h <<= 1) {
            #pragma unroll
            for (int i = 0; i < 32; i += 2 * h) {
                #pragma unroll
                for (int k = 0; k < h; ++k) {
                    float a = w[i + k], b = w[i + k + h];
                    w[i + k] = a + b;
                    w[i + k + h] = a - b;
                }
            }
        }
        const int rowbase = 32 * (32 * m + g);
        #pragma unroll
        for (int s = 0; s < 32; ++s)
            data[((size_t)(rowbase + s) << 15) + col] = w[s];
    }
}

extern "C" void kernel_launch(void* const* d_in, const int* in_sizes, int n_in,
                              void* d_out, int out_size, void* d_ws, size_t ws_size,
                              hipStream_t stream) {
    const float* x = (const float*)d_in[0];
    float* out = (float*)d_out;
    const size_t need = (size_t)1 << 27;             // 128 MB bf16 intermediate
    if (ws_size >= need && d_ws != nullptr) {
        fwht_low15_bf<<<2048, 512, 0, stream>>>(x, (uint2*)d_ws);
        fwht_high11_cb<<<1024, 1024, 0, stream>>>((const unsigned short*)d_ws, out);
    } else {
        fwht_low15_f32<<<2048, 512, 0, stream>>>(x, out);
        fwht_high11_f32<<<1024, 1024, 0, stream>>>(out);
    }
}